// Round 2
// baseline (847.689 us; speedup 1.0000x reference)
//
#include <hip/hip_runtime.h>

#define BB 8
#define SS 4096
#define HIDD 1024
#define HH 16
#define DHH 64

// K1: wq_eff[h][i] = sum_d aw[h,d] * Wq[h*64+d, i]   (and same for k)
// grid (4, 16, 2), block 256
__global__ __launch_bounds__(256) void k_prep(const float* __restrict__ Wq,
                                              const float* __restrict__ Wk,
                                              const float* __restrict__ aw,
                                              float* __restrict__ wq_f,
                                              float* __restrict__ wk_f) {
    int i = blockIdx.x * 256 + threadIdx.x;
    int h = blockIdx.y;
    const float* W = blockIdx.z ? Wk : Wq;
    float* outp = blockIdx.z ? wk_f : wq_f;
    float acc = 0.f;
#pragma unroll
    for (int d = 0; d < DHH; ++d) {
        acc += aw[h * DHH + d] * W[(size_t)(h * DHH + d) * HIDD + i];
    }
    outp[h * HIDD + i] = acc;
}

// K2: per-thread (row, head) full-1024 dot for q and k scores.
// grid 2048, block 256 (16 rows x 16 heads per block)
__global__ __launch_bounds__(256) void k_scores(const float* __restrict__ hid,
                                                const float* __restrict__ mask,
                                                const float* __restrict__ wq_f,
                                                const float* __restrict__ wk_f,
                                                float* __restrict__ qsb,
                                                float* __restrict__ ksb) {
    int h  = threadIdx.x & 15;
    int rl = threadIdx.x >> 4;
    int b  = blockIdx.x >> 8;                  // 256 blocks per batch
    int s  = ((blockIdx.x & 255) << 4) + rl;

    const float4* hp4 = reinterpret_cast<const float4*>(hid + (size_t)(b * SS + s) * HIDD);
    const float4* wq4 = reinterpret_cast<const float4*>(wq_f + h * HIDD);
    const float4* wk4 = reinterpret_cast<const float4*>(wk_f + h * HIDD);

    float aq = 0.f, ak = 0.f;
#pragma unroll 8
    for (int c = 0; c < HIDD / 4; ++c) {
        float4 hp = hp4[c];
        float4 q  = wq4[c];
        float4 k  = wk4[c];
        aq += hp.x * q.x + hp.y * q.y + hp.z * q.z + hp.w * q.w;
        ak += hp.x * k.x + hp.y * k.y + hp.z * k.z + hp.w * k.w;
    }
    float m = mask[b * SS + s];
    size_t row = (size_t)(b * SS + s);
    qsb[row * 16 + h] = aq * m;
    ksb[row * 20 + h] = ak * m;
    if (h == 0) ksb[row * 20 + 16] = m;
}

// K3: ksh[b,h,i] = sum_s k_score[b,s,h]*hidden[b,s,i];  hsum[b,i] = sum_s m*hidden[b,s,i]
// 17 channels (16 k + mask). grid (32, 2, 8), block 256, thread owns 2 i-columns, 128 s rows.
__global__ __launch_bounds__(256) void k_ksh(const float* __restrict__ hid,
                                             const float* __restrict__ ksb,
                                             float* __restrict__ ksh,
                                             float* __restrict__ hsum) {
    int b  = blockIdx.z;
    int i  = blockIdx.y * 512 + threadIdx.x * 2;
    int s0 = blockIdx.x * 128;

    float acc0[17], acc1[17];
#pragma unroll
    for (int c = 0; c < 17; ++c) { acc0[c] = 0.f; acc1[c] = 0.f; }

    for (int s = s0; s < s0 + 128; ++s) {
        const float* sc = ksb + (size_t)(b * SS + s) * 20;
        float2 hv = *reinterpret_cast<const float2*>(hid + (size_t)(b * SS + s) * HIDD + i);
#pragma unroll
        for (int c = 0; c < 17; ++c) {
            float scv = sc[c];
            acc0[c] += scv * hv.x;
            acc1[c] += scv * hv.y;
        }
    }
#pragma unroll
    for (int c = 0; c < 16; ++c) {
        atomicAdd(&ksh[((size_t)b * 16 + c) * HIDD + i], acc0[c]);
        atomicAdd(&ksh[((size_t)b * 16 + c) * HIDD + i + 1], acc1[c]);
    }
    atomicAdd(&hsum[b * HIDD + i], acc0[16]);
    atomicAdd(&hsum[b * HIDD + i + 1], acc1[16]);
}

// K4: mvn[b,j] = (Wv[j,:]·hsum[b,:]) / len[b];  kvn[b,j] = (Wv[j,:]·ksh[b,j/64,:]) / len[b]
// grid (8, 4), block 256
__global__ __launch_bounds__(256) void k_fin(const float* __restrict__ Wv,
                                             const float* __restrict__ mask,
                                             const float* __restrict__ hsum,
                                             const float* __restrict__ ksh,
                                             float* __restrict__ mvn,
                                             float* __restrict__ kvn) {
    int b = blockIdx.x;
    int j = blockIdx.y * 256 + threadIdx.x;

    __shared__ float red[256];
    float lsum = 0.f;
    for (int s = threadIdx.x; s < SS; s += 256) lsum += mask[b * SS + s];
    red[threadIdx.x] = lsum;
    __syncthreads();
    for (int off = 128; off; off >>= 1) {
        if (threadIdx.x < off) red[threadIdx.x] += red[threadIdx.x + off];
        __syncthreads();
    }
    float invlen = 1.0f / red[0];

    int h = j >> 6;
    const float4* w4 = reinterpret_cast<const float4*>(Wv + (size_t)j * HIDD);
    const float*  hs = hsum + b * HIDD;
    const float*  ks = ksh + ((size_t)b * 16 + h) * HIDD;

    float mv = 0.f, kv = 0.f;
    for (int c = 0; c < HIDD / 4; ++c) {
        float4 wp = w4[c];
        int i = c * 4;
        mv += wp.x * hs[i] + wp.y * hs[i + 1] + wp.z * hs[i + 2] + wp.w * hs[i + 3];
        kv += wp.x * ks[i] + wp.y * ks[i + 1] + wp.z * ks[i + 2] + wp.w * ks[i + 3];
    }
    mvn[b * HIDD + j] = mv * invlen;
    kvn[b * HIDD + j] = kv * invlen;
}

// K5: out[b,s,j] = q_score[b,s,j/64]*mvn[b,j] + kvn[b,j], float4 stores.
// grid 16384, block 256, 8 elems/thread
__global__ __launch_bounds__(256) void k_out(const float* __restrict__ qsb,
                                             const float* __restrict__ mvn,
                                             const float* __restrict__ kvn,
                                             float* __restrict__ outp) {
    size_t e0 = ((size_t)blockIdx.x * 256 + threadIdx.x) * 8;
    int b   = (int)(e0 >> 22);                 // 4096*1024 = 2^22
    int rem = (int)(e0 & ((1u << 22) - 1));
    int s   = rem >> 10;
    int j   = rem & 1023;

    float q = qsb[(size_t)(b * SS + s) * 16 + (j >> 6)];
    const float4* mv4 = reinterpret_cast<const float4*>(mvn + b * HIDD + j);
    const float4* kv4 = reinterpret_cast<const float4*>(kvn + b * HIDD + j);
    float4 m0 = mv4[0], m1 = mv4[1];
    float4 k0 = kv4[0], k1 = kv4[1];

    float4 o0, o1;
    o0.x = q * m0.x + k0.x;  o0.y = q * m0.y + k0.y;
    o0.z = q * m0.z + k0.z;  o0.w = q * m0.w + k0.w;
    o1.x = q * m1.x + k1.x;  o1.y = q * m1.y + k1.y;
    o1.z = q * m1.z + k1.z;  o1.w = q * m1.w + k1.w;

    float4* op = reinterpret_cast<float4*>(outp + e0);
    op[0] = o0;
    op[1] = o1;
}

extern "C" void kernel_launch(void* const* d_in, const int* in_sizes, int n_in,
                              void* d_out, int out_size, void* d_ws, size_t ws_size,
                              hipStream_t stream) {
    const float* hid  = (const float*)d_in[0];   // (B,S,HID)
    const float* mask = (const float*)d_in[1];   // (B,1,1,S)
    const float* Wq   = (const float*)d_in[2];   // (HID,HID)
    const float* Wk   = (const float*)d_in[3];
    const float* Wv   = (const float*)d_in[4];
    const float* aw   = (const float*)d_in[5];   // (H,1,DH)
    float* outp = (float*)d_out;

    float* ws   = (float*)d_ws;
    float* wq_f = ws;                       // 16384
    float* wk_f = wq_f + 16384;             // 16384
    float* qsb  = wk_f + 16384;             // 8*4096*16 = 524288
    float* ksb  = qsb + 524288;             // 8*4096*20 = 655360
    float* ksh  = ksb + 655360;             // 8*16*1024 = 131072
    float* hsum = ksh + 131072;             // 8*1024   = 8192
    float* mvn  = hsum + 8192;              // 8192
    float* kvn  = mvn + 8192;               // 8192

    // zero the atomic accumulators (ksh + hsum are adjacent)
    hipMemsetAsync(ksh, 0, (131072 + 8192) * sizeof(float), stream);

    k_prep  <<<dim3(4, 16, 2), 256, 0, stream>>>(Wq, Wk, aw, wq_f, wk_f);
    k_scores<<<dim3(2048),     256, 0, stream>>>(hid, mask, wq_f, wk_f, qsb, ksb);
    k_ksh   <<<dim3(32, 2, 8), 256, 0, stream>>>(hid, ksb, ksh, hsum);
    k_fin   <<<dim3(8, 4),     256, 0, stream>>>(Wv, mask, hsum, ksh, mvn, kvn);
    k_out   <<<dim3(16384),    256, 0, stream>>>(qsb, mvn, kvn, outp);
}

// Round 3
// 461.672 us; speedup vs baseline: 1.8361x; 1.8361x over previous
//
#include <hip/hip_runtime.h>

#define BB 8
#define SS 4096
#define HIDD 1024
#define HH 16
#define DHH 64

// K1: weff[o][i], o<16: sum_d aw[o,d]*Wq[o*64+d, i]; o>=16: same with Wk.
// wq_f and wk_f are adjacent in ws => weff = wq_f is [32][1024].
// grid (4, 16, 2), block 256
__global__ __launch_bounds__(256) void k_prep(const float* __restrict__ Wq,
                                              const float* __restrict__ Wk,
                                              const float* __restrict__ aw,
                                              float* __restrict__ wq_f,
                                              float* __restrict__ wk_f) {
    int i = blockIdx.x * 256 + threadIdx.x;
    int h = blockIdx.y;
    const float* W = blockIdx.z ? Wk : Wq;
    float* outp = blockIdx.z ? wk_f : wq_f;
    float acc = 0.f;
#pragma unroll
    for (int d = 0; d < DHH; ++d) {
        acc += aw[h * DHH + d] * W[(size_t)(h * DHH + d) * HIDD + i];
    }
    outp[h * HIDD + i] = acc;
}

// K2 v3: tall-skinny GEMM  scores[32768 rows][32 outs] = hid x weff^T.
// Block 256 = 4 waves, owns 64 rows. lane = row. wave og owns outs og*8..og*8+7
// (outs 0..15 = q heads, 16..31 = k heads). Hid chunk (64x128) staged in LDS
// with stride 129 (2-way bank aliasing = free). Weights read via wave-uniform
// pointers -> scalar cache (s_load), no VMEM scatter.
#define KC 128
#define LSTR 129
__global__ __launch_bounds__(256) void k_scores(const float* __restrict__ hid,
                                                const float* __restrict__ mask,
                                                const float* __restrict__ weff,
                                                float* __restrict__ qsb,
                                                float* __restrict__ ksb) {
    __shared__ float sh[64 * LSTR];

    const int t    = threadIdx.x;
    const int wave = t >> 6;
    const int lane = t & 63;
    const int obase = __builtin_amdgcn_readfirstlane(wave * 8);

    const int row  = blockIdx.x * 64 + lane;       // global row (b*4096+s)
    const size_t gbase = (size_t)blockIdx.x * 64 * HIDD;

    float acc[8];
#pragma unroll
    for (int o = 0; o < 8; ++o) acc[o] = 0.f;

    for (int chunk = 0; chunk < HIDD / KC; ++chunk) {
        __syncthreads();
        // stage 64 rows x 128 cols: 2048 float4s, 8 per thread, coalesced
#pragma unroll
        for (int j = 0; j < 8; ++j) {
            int f   = j * 256 + t;
            int r   = f >> 5;          // 32 float4 per row
            int c4  = f & 31;
            float4 v = *reinterpret_cast<const float4*>(
                hid + gbase + (size_t)r * HIDD + chunk * KC + c4 * 4);
            float* d = sh + r * LSTR + c4 * 4;
            d[0] = v.x; d[1] = v.y; d[2] = v.z; d[3] = v.w;
        }
        __syncthreads();

        const float* wc = weff + chunk * KC;
#pragma unroll 8
        for (int k = 0; k < KC; k += 4) {
            float h0 = sh[lane * LSTR + k];
            float h1 = sh[lane * LSTR + k + 1];
            float h2 = sh[lane * LSTR + k + 2];
            float h3 = sh[lane * LSTR + k + 3];
#pragma unroll
            for (int o = 0; o < 8; ++o) {
                float4 wv = *reinterpret_cast<const float4*>(
                    wc + (size_t)(obase + o) * HIDD + k);
                acc[o] += h0 * wv.x + h1 * wv.y + h2 * wv.z + h3 * wv.w;
            }
        }
    }

    float m = mask[row];               // mask is (B,1,1,S) = flat 32768
#pragma unroll
    for (int o = 0; o < 8; ++o) acc[o] *= m;

    if (obase < 16) {
        // q scores: heads obase..obase+7, contiguous in qsb[row][16]
        float4 v0 = make_float4(acc[0], acc[1], acc[2], acc[3]);
        float4 v1 = make_float4(acc[4], acc[5], acc[6], acc[7]);
        float4* p = reinterpret_cast<float4*>(qsb + (size_t)row * 16 + obase);
        p[0] = v0; p[1] = v1;
    } else {
        int hb = obase - 16;
        float4 v0 = make_float4(acc[0], acc[1], acc[2], acc[3]);
        float4 v1 = make_float4(acc[4], acc[5], acc[6], acc[7]);
        float4* p = reinterpret_cast<float4*>(ksb + (size_t)row * 20 + hb);
        p[0] = v0; p[1] = v1;
    }
    if (obase == 0) ksb[(size_t)row * 20 + 16] = m;
}

// K3: ksh[b,h,i] = sum_s k_score[b,s,h]*hidden[b,s,i];  hsum[b,i] = sum_s m*hidden[b,s,i]
// 17 channels (16 k + mask). grid (32, 2, 8), block 256, thread owns 2 i-columns, 128 s rows.
__global__ __launch_bounds__(256) void k_ksh(const float* __restrict__ hid,
                                             const float* __restrict__ ksb,
                                             float* __restrict__ ksh,
                                             float* __restrict__ hsum) {
    int b  = blockIdx.z;
    int i  = blockIdx.y * 512 + threadIdx.x * 2;
    int s0 = blockIdx.x * 128;

    float acc0[17], acc1[17];
#pragma unroll
    for (int c = 0; c < 17; ++c) { acc0[c] = 0.f; acc1[c] = 0.f; }

    for (int s = s0; s < s0 + 128; ++s) {
        const float* sc = ksb + (size_t)(b * SS + s) * 20;
        float2 hv = *reinterpret_cast<const float2*>(hid + (size_t)(b * SS + s) * HIDD + i);
#pragma unroll
        for (int c = 0; c < 17; ++c) {
            float scv = sc[c];
            acc0[c] += scv * hv.x;
            acc1[c] += scv * hv.y;
        }
    }
#pragma unroll
    for (int c = 0; c < 16; ++c) {
        atomicAdd(&ksh[((size_t)b * 16 + c) * HIDD + i], acc0[c]);
        atomicAdd(&ksh[((size_t)b * 16 + c) * HIDD + i + 1], acc1[c]);
    }
    atomicAdd(&hsum[b * HIDD + i], acc0[16]);
    atomicAdd(&hsum[b * HIDD + i + 1], acc1[16]);
}

// K4: mvn[b,j] = (Wv[j,:]·hsum[b,:]) / len[b];  kvn[b,j] = (Wv[j,:]·ksh[b,j/64,:]) / len[b]
// grid (8, 4), block 256
__global__ __launch_bounds__(256) void k_fin(const float* __restrict__ Wv,
                                             const float* __restrict__ mask,
                                             const float* __restrict__ hsum,
                                             const float* __restrict__ ksh,
                                             float* __restrict__ mvn,
                                             float* __restrict__ kvn) {
    int b = blockIdx.x;
    int j = blockIdx.y * 256 + threadIdx.x;

    __shared__ float red[256];
    float lsum = 0.f;
    for (int s = threadIdx.x; s < SS; s += 256) lsum += mask[b * SS + s];
    red[threadIdx.x] = lsum;
    __syncthreads();
    for (int off = 128; off; off >>= 1) {
        if (threadIdx.x < off) red[threadIdx.x] += red[threadIdx.x + off];
        __syncthreads();
    }
    float invlen = 1.0f / red[0];

    int h = j >> 6;
    const float4* w4 = reinterpret_cast<const float4*>(Wv + (size_t)j * HIDD);
    const float*  hs = hsum + b * HIDD;
    const float*  ks = ksh + ((size_t)b * 16 + h) * HIDD;

    float mv = 0.f, kv = 0.f;
    for (int c = 0; c < HIDD / 4; ++c) {
        float4 wp = w4[c];
        int i = c * 4;
        mv += wp.x * hs[i] + wp.y * hs[i + 1] + wp.z * hs[i + 2] + wp.w * hs[i + 3];
        kv += wp.x * ks[i] + wp.y * ks[i + 1] + wp.z * ks[i + 2] + wp.w * ks[i + 3];
    }
    mvn[b * HIDD + j] = mv * invlen;
    kvn[b * HIDD + j] = kv * invlen;
}

// K5: out[b,s,j] = q_score[b,s,j/64]*mvn[b,j] + kvn[b,j], float4 stores.
// grid 16384, block 256, 8 elems/thread
__global__ __launch_bounds__(256) void k_out(const float* __restrict__ qsb,
                                             const float* __restrict__ mvn,
                                             const float* __restrict__ kvn,
                                             float* __restrict__ outp) {
    size_t e0 = ((size_t)blockIdx.x * 256 + threadIdx.x) * 8;
    int b   = (int)(e0 >> 22);                 // 4096*1024 = 2^22
    int rem = (int)(e0 & ((1u << 22) - 1));
    int s   = rem >> 10;
    int j   = rem & 1023;

    float q = qsb[(size_t)(b * SS + s) * 16 + (j >> 6)];
    const float4* mv4 = reinterpret_cast<const float4*>(mvn + b * HIDD + j);
    const float4* kv4 = reinterpret_cast<const float4*>(kvn + b * HIDD + j);
    float4 m0 = mv4[0], m1 = mv4[1];
    float4 k0 = kv4[0], k1 = kv4[1];

    float4 o0, o1;
    o0.x = q * m0.x + k0.x;  o0.y = q * m0.y + k0.y;
    o0.z = q * m0.z + k0.z;  o0.w = q * m0.w + k0.w;
    o1.x = q * m1.x + k1.x;  o1.y = q * m1.y + k1.y;
    o1.z = q * m1.z + k1.z;  o1.w = q * m1.w + k1.w;

    float4* op = reinterpret_cast<float4*>(outp + e0);
    op[0] = o0;
    op[1] = o1;
}

extern "C" void kernel_launch(void* const* d_in, const int* in_sizes, int n_in,
                              void* d_out, int out_size, void* d_ws, size_t ws_size,
                              hipStream_t stream) {
    const float* hid  = (const float*)d_in[0];   // (B,S,HID)
    const float* mask = (const float*)d_in[1];   // (B,1,1,S)
    const float* Wq   = (const float*)d_in[2];   // (HID,HID)
    const float* Wk   = (const float*)d_in[3];
    const float* Wv   = (const float*)d_in[4];
    const float* aw   = (const float*)d_in[5];   // (H,1,DH)
    float* outp = (float*)d_out;

    float* ws   = (float*)d_ws;
    float* wq_f = ws;                       // 16384   } weff[32][1024]
    float* wk_f = wq_f + 16384;             // 16384   } (adjacent)
    float* qsb  = wk_f + 16384;             // 8*4096*16 = 524288
    float* ksb  = qsb + 524288;             // 8*4096*20 = 655360
    float* ksh  = ksb + 655360;             // 8*16*1024 = 131072
    float* hsum = ksh + 131072;             // 8*1024   = 8192
    float* mvn  = hsum + 8192;              // 8192
    float* kvn  = mvn + 8192;               // 8192

    // zero the atomic accumulators (ksh + hsum are adjacent)
    hipMemsetAsync(ksh, 0, (131072 + 8192) * sizeof(float), stream);

    k_prep  <<<dim3(4, 16, 2), 256, 0, stream>>>(Wq, Wk, aw, wq_f, wk_f);
    k_scores<<<dim3(512),      256, 0, stream>>>(hid, mask, wq_f, qsb, ksb);
    k_ksh   <<<dim3(32, 2, 8), 256, 0, stream>>>(hid, ksb, ksh, hsum);
    k_fin   <<<dim3(8, 4),     256, 0, stream>>>(Wv, mask, hsum, ksh, mvn, kvn);
    k_out   <<<dim3(16384),    256, 0, stream>>>(qsb, mvn, kvn, outp);
}